// Round 9
// baseline (17.833 us; speedup 1.0000x reference)
//
#include <hip/hip_runtime.h>

// Problem constants (from reference)
#define B_    2
#define H1_   64
#define W1_   96
#define H2_   64
#define W2_   96
#define HW_   (H1_ * W1_)          // 6144, also H2*W2
#define KWIN  81                   // 9x9 lookup window
#define CORR_ELEMS (B_ * KWIN * HW_)              // 995328
#define UP_HW      (8 * H1_ * 8 * W1_)            // 512*768

#define CORR_PIX    (B_ * HW_)                    // 12288 pixels
#define CORR_BLOCKS (CORR_PIX / 128)              // 96 blocks, 128 pixels each
#define UP_BLOCKS   (B_ * 8 * 12)                 // 192 blocks: (n, r, 512-pos hw-span)
#define TOT_BLOCKS  (CORR_BLOCKS + UP_BLOCKS)     // 288, 512-thread blocks

#define PSTRIDE 101                               // LDS stride per pixel (coprime w/ 32)

typedef float float4n __attribute__((ext_vector_type(4)));   // native vec for nontemporal

// ---------------------------------------------------------------------------
// Fused kernel, 512-thread blocks.
//  blocks [0, 96): corr — 128 pixels/block, LDS-staged two-phase (8 waves).
//      Per-channel store = 512 B contiguous (2 adjacent waves) vs 256 B before.
//  blocks [96, 288): convex upsample — block = (n, r, flat 512-pos hw-span);
//      per-channel mask read = 2 KB contiguous per block.
// Streams cost/mask read-once -> nontemporal loads; out write-once ->
// nontemporal stores. coords/flow reused -> normal cached loads.
// ---------------------------------------------------------------------------
__global__ __launch_bounds__(512) void fused_kernel(const float* __restrict__ cost,
                                                    const float* __restrict__ coords,
                                                    const float* __restrict__ flow,
                                                    const float* __restrict__ mask,
                                                    float* __restrict__ out) {
    __shared__ float patch[128 * PSTRIDE];         // 51.7 KB
    __shared__ int   xi0s[128];
    __shared__ int   yi0s[128];

    if (blockIdx.x < CORR_BLOCKS) {
        // ---------------- corr ----------------
        int cid  = blockIdx.x;
        int tid  = threadIdx.x;
        int px   = tid & 127;                       // pixel within block
        int g    = tid >> 7;                        // channel group, 0..3
        int m    = cid * 128 + px;                  // global pixel id
        int b    = m / HW_;                         // uniform per block (6144%128==0)
        int rem  = m - b * HW_;

        // phase 0: per-pixel params (4 groups compute the same, lane=px)
        float cx = coords[b * 2 * HW_ + rem];
        float cy = coords[b * 2 * HW_ + HW_ + rem];
        float xf = floorf(cx), yf = floorf(cy);
        float wx = cx - xf,   wy = cy - yf;
        int xi0 = (int)xf - 4;
        int yi0 = (int)yf - 4;
        float w00 = (1.0f - wx) * (1.0f - wy);
        float w10 = wx * (1.0f - wy);
        float w01 = (1.0f - wx) * wy;
        float w11 = wx * wy;

        if (tid < 128) { xi0s[tid] = xi0; yi0s[tid] = yi0; }
        __syncthreads();

        // phase 1: cooperative patch load — 128 px * 100 elems = 12800 = 25*512
        const float* __restrict__ cmB = cost + (size_t)cid * 128 * HW_;
#pragma unroll
        for (int it = 0; it < 25; ++it) {
            unsigned l  = it * 512u + tid;
            unsigned pl = l / 100u;
            unsigned e  = l - pl * 100u;
            unsigned r  = e / 10u;
            unsigned c  = e - r * 10u;
            int y = yi0s[pl] + (int)r;
            int x = xi0s[pl] + (int)c;
            bool ok = (x >= 0) & (x < W2_) & (y >= 0) & (y < H2_);
            int yc = min(max(y, 0), H2_ - 1);
            int xc = min(max(x, 0), W2_ - 1);
            float v = __builtin_nontemporal_load(cmB + pl * HW_ + yc * W2_ + xc);
            patch[pl * PSTRIDE + e] = ok ? v : 0.0f;
        }
        __syncthreads();

        // phase 2: group g computes contiguous channel chunk; px = pixel
        const float* __restrict__ pp = patch + px * PSTRIDE;
        size_t obase = (size_t)b * KWIN * HW_ + rem;
        int start = (g == 0) ? 0 : (1 + 20 * g);    // 0,21,41,61
        int count = (g == 0) ? 21 : 20;
        for (int t = 0; t < count; ++t) {
            int ch = start + t;                      // group-uniform
            int p  = ch / 9;
            int q  = ch - p * 9;
            int o  = q * 10 + p;
            float val = w00 * pp[o]      + w10 * pp[o + 1]
                      + w01 * pp[o + 10] + w11 * pp[o + 11];
            __builtin_nontemporal_store(val, out + obase + (size_t)ch * HW_);
        }
    } else {
        // ---------------- convex upsample ----------------
        int uid = blockIdx.x - CORR_BLOCKS;          // [0, 192)
        int seg = uid % 12;                          // hw-span
        int r   = (uid / 12) & 7;
        int n   = uid / 96;
        int hw  = seg * 512 + threadIdx.x;           // flat h*96+w, [0, 6144)
        int h   = hw / 96;
        int w   = hw - h * 96;

        // mask: [B, 576, H1, W1]; channel = k*64 + r*8 + s
        const float* __restrict__ mp = mask + ((size_t)n * 576 + r * 8) * HW_ + hw;
        float mv[9][8];
#pragma unroll
        for (int k = 0; k < 9; ++k)
#pragma unroll
            for (int s = 0; s < 8; ++s)
                mv[k][s] = __builtin_nontemporal_load(mp + (size_t)(k * 64 + s) * HW_);

        float scale[8];
#pragma unroll
        for (int s = 0; s < 8; ++s) {
            float mx = mv[0][s];
#pragma unroll
            for (int k = 1; k < 9; ++k) mx = fmaxf(mx, mv[k][s]);
            float sum = 0.0f;
#pragma unroll
            for (int k = 0; k < 9; ++k) { mv[k][s] = __expf(mv[k][s] - mx); sum += mv[k][s]; }
            scale[s] = 8.0f / sum;
        }

        const float* __restrict__ f0p = flow + (size_t)n * 2 * HW_;
        const float* __restrict__ f1p = f0p + HW_;
        float a0[8], a1[8];
#pragma unroll
        for (int s = 0; s < 8; ++s) { a0[s] = 0.0f; a1[s] = 0.0f; }

#pragma unroll
        for (int di = 0; di < 3; ++di) {
#pragma unroll
            for (int dj = 0; dj < 3; ++dj) {
                int k = di * 3 + dj;
                int hx = h + di - 1, wwp = w + dj - 1;
                bool ok = (hx >= 0) & (hx < H1_) & (wwp >= 0) & (wwp < W1_);
                float fv0 = ok ? f0p[hx * W1_ + wwp] : 0.0f;
                float fv1 = ok ? f1p[hx * W1_ + wwp] : 0.0f;
#pragma unroll
                for (int s = 0; s < 8; ++s) {
                    a0[s] += mv[k][s] * fv0;
                    a1[s] += mv[k][s] * fv1;
                }
            }
        }

        float* outU = out + CORR_ELEMS;
        size_t ob = ((size_t)(n * 2 + 0) * (8 * H1_) + h * 8 + r) * (8 * W1_) + (size_t)w * 8;
        float4n c0a = { a0[0] * scale[0], a0[1] * scale[1], a0[2] * scale[2], a0[3] * scale[3] };
        float4n c0b = { a0[4] * scale[4], a0[5] * scale[5], a0[6] * scale[6], a0[7] * scale[7] };
        float4n c1a = { a1[0] * scale[0], a1[1] * scale[1], a1[2] * scale[2], a1[3] * scale[3] };
        float4n c1b = { a1[4] * scale[4], a1[5] * scale[5], a1[6] * scale[6], a1[7] * scale[7] };
        __builtin_nontemporal_store(c0a, (float4n*)(outU + ob));
        __builtin_nontemporal_store(c0b, (float4n*)(outU + ob + 4));
        __builtin_nontemporal_store(c1a, (float4n*)(outU + ob + UP_HW));
        __builtin_nontemporal_store(c1b, (float4n*)(outU + ob + UP_HW + 4));
    }
}

extern "C" void kernel_launch(void* const* d_in, const int* in_sizes, int n_in,
                              void* d_out, int out_size, void* d_ws, size_t ws_size,
                              hipStream_t stream) {
    const float* cost   = (const float*)d_in[0];   // [12288, 1, 64, 96]
    const float* coords = (const float*)d_in[1];   // [2, 2, 64, 96]
    const float* flow   = (const float*)d_in[2];   // [2, 2, 64, 96]
    const float* mask   = (const float*)d_in[3];   // [2, 576, 64, 96]
    float* out = (float*)d_out;                    // corr (995328) ++ up_flow (1572864)

    fused_kernel<<<TOT_BLOCKS, 512, 0, stream>>>(cost, coords, flow, mask, out);
}

// Round 10
// 14.461 us; speedup vs baseline: 1.2332x; 1.2332x over previous
//
#include <hip/hip_runtime.h>

// Problem constants (from reference)
#define B_    2
#define H1_   64
#define W1_   96
#define H2_   64
#define W2_   96
#define HW_   (H1_ * W1_)          // 6144, also H2*W2
#define KWIN  81                   // 9x9 lookup window
#define CORR_ELEMS (B_ * KWIN * HW_)              // 995328
#define UP_HW      (8 * H1_ * 8 * W1_)            // 512*768

#define CORR_PIX    (B_ * HW_)                    // 12288 pixels
#define CORR_BLOCKS (CORR_PIX / 64)               // 192 blocks, 64 pixels each
#define UP_BLOCKS   (B_ * 8 * 16)                 // 256 blocks: (n, r, h-tile of 4)
#define TOT_BLOCKS  (CORR_BLOCKS + UP_BLOCKS)     // 448, 384-thread blocks

#define PSTRIDE 101                               // LDS stride per pixel (coprime w/ 32)

typedef float float4n __attribute__((ext_vector_type(4)));   // native vec for nontemporal

// ---------------------------------------------------------------------------
// Fused kernel, 384-thread blocks (round-8 configuration — best measured).
//  blocks [0, 192): corr — 64 pixels/block, LDS-staged two-phase (6 waves)
//  blocks [192, 448): convex upsample — block = (n, r, 4-row h-tile);
//      thread (w, hh) does all 8 s + both channels; per-channel mask read =
//      1536 B contiguous.
// Streams cost/mask read-once -> nontemporal loads; out write-once ->
// nontemporal stores. coords/flow reused -> normal cached loads.
// ---------------------------------------------------------------------------
__global__ __launch_bounds__(384) void fused_kernel(const float* __restrict__ cost,
                                                    const float* __restrict__ coords,
                                                    const float* __restrict__ flow,
                                                    const float* __restrict__ mask,
                                                    float* __restrict__ out) {
    __shared__ float patch[64 * PSTRIDE];          // 25.9 KB
    __shared__ int   xi0s[64];
    __shared__ int   yi0s[64];

    if (blockIdx.x < CORR_BLOCKS) {
        // ---------------- corr ----------------
        int tid  = threadIdx.x;
        int lane = tid & 63;
        int g    = tid >> 6;                        // wave id, 0..5
        int m    = blockIdx.x * 64 + lane;          // this lane's pixel (phase 0/2)
        int b    = m / HW_;                         // uniform per block
        int rem  = m - b * HW_;

        // phase 0: per-pixel params (all 6 waves compute the same, lane=px)
        float cx = coords[b * 2 * HW_ + rem];
        float cy = coords[b * 2 * HW_ + HW_ + rem];
        float xf = floorf(cx), yf = floorf(cy);
        float wx = cx - xf,   wy = cy - yf;
        int xi0 = (int)xf - 4;
        int yi0 = (int)yf - 4;
        float w00 = (1.0f - wx) * (1.0f - wy);
        float w10 = wx * (1.0f - wy);
        float w01 = (1.0f - wx) * wy;
        float w11 = wx * wy;

        if (tid < 64) { xi0s[tid] = xi0; yi0s[tid] = yi0; }
        __syncthreads();

        // phase 1: cooperative patch load — 64 px * 100 elems = 6400
        const float* __restrict__ cmB = cost + (size_t)blockIdx.x * 64 * HW_;
#pragma unroll
        for (int it = 0; it < 17; ++it) {
            int l = it * 384 + tid;
            if (l < 6400) {
                unsigned px = (unsigned)l / 100u;
                unsigned e  = (unsigned)l - px * 100u;
                unsigned r  = e / 10u;
                unsigned c  = e - r * 10u;
                int y = yi0s[px] + (int)r;
                int x = xi0s[px] + (int)c;
                bool ok = (x >= 0) & (x < W2_) & (y >= 0) & (y < H2_);
                int yc = min(max(y, 0), H2_ - 1);
                int xc = min(max(x, 0), W2_ - 1);
                float v = __builtin_nontemporal_load(cmB + px * HW_ + yc * W2_ + xc);
                patch[px * PSTRIDE + e] = ok ? v : 0.0f;
            }
        }
        __syncthreads();

        // phase 2: wave g computes contiguous channel chunk; lane = pixel
        const float* __restrict__ pp = patch + lane * PSTRIDE;
        size_t obase = (size_t)b * KWIN * HW_ + rem;
        int start = (g < 3) ? 14 * g : 42 + 13 * (g - 3);   // 0,14,28,42,55,68
        int count = (g < 3) ? 14 : 13;
        for (int t = 0; t < count; ++t) {
            int ch = start + t;                      // wave-uniform
            int p  = ch / 9;
            int q  = ch - p * 9;
            int o  = q * 10 + p;
            float val = w00 * pp[o]      + w10 * pp[o + 1]
                      + w01 * pp[o + 10] + w11 * pp[o + 11];
            __builtin_nontemporal_store(val, out + obase + (size_t)ch * HW_);
        }
    } else {
        // ---------------- convex upsample ----------------
        int uid = blockIdx.x - CORR_BLOCKS;          // [0, 256)
        int ht = uid & 15;                           // h-tile (4 rows)
        int r  = (uid >> 4) & 7;
        int n  = uid >> 7;
        int w  = threadIdx.x % 96;
        int hh = threadIdx.x / 96;                   // 0..3
        int h  = ht * 4 + hh;

        // mask: [B, 576, H1, W1]; channel = k*64 + r*8 + s
        const float* __restrict__ mp = mask + ((size_t)n * 576 + r * 8) * HW_ + h * W1_ + w;
        float mv[9][8];
#pragma unroll
        for (int k = 0; k < 9; ++k)
#pragma unroll
            for (int s = 0; s < 8; ++s)
                mv[k][s] = __builtin_nontemporal_load(mp + (size_t)(k * 64 + s) * HW_);

        float scale[8];
#pragma unroll
        for (int s = 0; s < 8; ++s) {
            float mx = mv[0][s];
#pragma unroll
            for (int k = 1; k < 9; ++k) mx = fmaxf(mx, mv[k][s]);
            float sum = 0.0f;
#pragma unroll
            for (int k = 0; k < 9; ++k) { mv[k][s] = __expf(mv[k][s] - mx); sum += mv[k][s]; }
            scale[s] = 8.0f / sum;
        }

        const float* __restrict__ f0p = flow + (size_t)n * 2 * HW_;
        const float* __restrict__ f1p = f0p + HW_;
        float a0[8], a1[8];
#pragma unroll
        for (int s = 0; s < 8; ++s) { a0[s] = 0.0f; a1[s] = 0.0f; }

#pragma unroll
        for (int di = 0; di < 3; ++di) {
#pragma unroll
            for (int dj = 0; dj < 3; ++dj) {
                int k = di * 3 + dj;
                int hx = h + di - 1, wwp = w + dj - 1;
                bool ok = (hx >= 0) & (hx < H1_) & (wwp >= 0) & (wwp < W1_);
                float fv0 = ok ? f0p[hx * W1_ + wwp] : 0.0f;
                float fv1 = ok ? f1p[hx * W1_ + wwp] : 0.0f;
#pragma unroll
                for (int s = 0; s < 8; ++s) {
                    a0[s] += mv[k][s] * fv0;
                    a1[s] += mv[k][s] * fv1;
                }
            }
        }

        float* outU = out + CORR_ELEMS;
        size_t ob = ((size_t)(n * 2 + 0) * (8 * H1_) + h * 8 + r) * (8 * W1_) + (size_t)w * 8;
        float4n c0a = { a0[0] * scale[0], a0[1] * scale[1], a0[2] * scale[2], a0[3] * scale[3] };
        float4n c0b = { a0[4] * scale[4], a0[5] * scale[5], a0[6] * scale[6], a0[7] * scale[7] };
        float4n c1a = { a1[0] * scale[0], a1[1] * scale[1], a1[2] * scale[2], a1[3] * scale[3] };
        float4n c1b = { a1[4] * scale[4], a1[5] * scale[5], a1[6] * scale[6], a1[7] * scale[7] };
        __builtin_nontemporal_store(c0a, (float4n*)(outU + ob));
        __builtin_nontemporal_store(c0b, (float4n*)(outU + ob + 4));
        __builtin_nontemporal_store(c1a, (float4n*)(outU + ob + UP_HW));
        __builtin_nontemporal_store(c1b, (float4n*)(outU + ob + UP_HW + 4));
    }
}

extern "C" void kernel_launch(void* const* d_in, const int* in_sizes, int n_in,
                              void* d_out, int out_size, void* d_ws, size_t ws_size,
                              hipStream_t stream) {
    const float* cost   = (const float*)d_in[0];   // [12288, 1, 64, 96]
    const float* coords = (const float*)d_in[1];   // [2, 2, 64, 96]
    const float* flow   = (const float*)d_in[2];   // [2, 2, 64, 96]
    const float* mask   = (const float*)d_in[3];   // [2, 576, 64, 96]
    float* out = (float*)d_out;                    // corr (995328) ++ up_flow (1572864)

    fused_kernel<<<TOT_BLOCKS, 384, 0, stream>>>(cost, coords, flow, mask, out);
}